// Round 1
// 89.912 us; speedup vs baseline: 1.4193x; 1.4193x over previous
//
#include <hip/hip_runtime.h>

// OverlapCalculator: pairwise IoU [50000 x 2000] fp32, row max + argmax.
// Outputs (flat fp32): pred_bbox[200000] | gt_bbox[8000] | max[50000] | argmax-as-float[50000]
//
// Spatially-pruned, bit-exact vs numpy fp32:
//  A pair can have inter > 0 only if g.x in (p.x - maxgw, p.z)  (maxgw = max
//  gt width). Every gt outside that window yields w = max(min-max, 0) = 0
//  EXACTLY -> iou = 0/un = 0 exactly, so it can't affect the row max; and if
//  the row max is 0 then iou[0] == 0 -> ref argmax = 0, matched by our init
//  (best,bidx) = (0,0). So it suffices to scan the window candidates with the
//  EXACT reference fp expression (contract off, IEEE divide) and keep a
//  lexicographic (q, -orig_idx) running max => bit-exact max + numpy
//  first-occurrence argmax.
//
//  build_index (1 block): counting-sort gts by g.x into NBIN bins, compute
//    xmin / inv-binwidth / maxgw, write sorted gt + orig idx + bin starts to
//    ws; gt passthrough.
//  iou_max (1563 blocks x 256): stage sorted table in LDS (38 KB -> 4
//    blocks/CU), 8 lanes per pred scan the pred's bin window (~315 of 2000
//    gts), shfl_xor lex-reduce within the 8-lane group; pred passthrough.

#define N_PRED 50000
#define N_GT   2000
#define NBIN   512
#define BLOCK  256
#define LPP    8               // lanes cooperating on one pred
#define PPB    (BLOCK / LPP)   // 32 preds per block

__device__ __forceinline__ int bin_of(float x, float xmin, float invw) {
    int b = (int)floorf((x - xmin) * invw);
    return max(0, min(NBIN - 1, b));
}

// --- setup: counting-sort 2000 gts by left edge; 1 block of 512 ------------
__global__ __launch_bounds__(512) void build_index(
        const float4* __restrict__ gt,
        float4* __restrict__ ws_gt, unsigned short* __restrict__ ws_idx,
        int* __restrict__ ws_bin, float* __restrict__ ws_par,
        float* __restrict__ out) {
#pragma clang fp contract(off)
    __shared__ float rmin[512], rmax[512], rw[512];
    __shared__ int   hist[NBIN], scan[NBIN], cursor[NBIN];
    __shared__ float s_par[3];
    const int tid = threadIdx.x;

    float mn = 3.4e38f, mx = -3.4e38f, mw = 0.0f;
    for (int j = tid; j < N_GT; j += 512) {
        const float4 g = gt[j];
        mn = fminf(mn, g.x);
        mx = fmaxf(mx, g.x);
        mw = fmaxf(mw, g.z - g.x);
        ((float4*)(out + 4 * N_PRED))[j] = g;    // gt passthrough
    }
    rmin[tid] = mn; rmax[tid] = mx; rw[tid] = mw;
    __syncthreads();
    for (int s = 256; s > 0; s >>= 1) {
        if (tid < s) {
            rmin[tid] = fminf(rmin[tid], rmin[tid + s]);
            rmax[tid] = fmaxf(rmax[tid], rmax[tid + s]);
            rw[tid]   = fmaxf(rw[tid],   rw[tid + s]);
        }
        __syncthreads();
    }
    if (tid == 0) {
        const float xmin  = rmin[0];
        const float range = fmaxf(rmax[0] - xmin, 1e-20f);
        s_par[0] = xmin;
        s_par[1] = (float)NBIN / range;
        s_par[2] = rw[0];
        ws_par[0] = s_par[0]; ws_par[1] = s_par[1]; ws_par[2] = s_par[2];
    }
    hist[tid] = 0;                               // NBIN == blockDim
    __syncthreads();
    const float xmin = s_par[0], invw = s_par[1];

    for (int j = tid; j < N_GT; j += 512)
        atomicAdd(&hist[bin_of(gt[j].x, xmin, invw)], 1);
    __syncthreads();

    // inclusive Hillis-Steele scan over NBIN == 512 entries
    const int v = hist[tid];
    scan[tid] = v;
    __syncthreads();
    for (int off = 1; off < NBIN; off <<= 1) {
        const int t = (tid >= off) ? scan[tid - off] : 0;
        __syncthreads();
        scan[tid] += t;
        __syncthreads();
    }
    const int excl = scan[tid] - v;
    cursor[tid] = excl;
    ws_bin[tid] = excl;
    if (tid == NBIN - 1) ws_bin[NBIN] = scan[tid];
    __syncthreads();

    for (int j = tid; j < N_GT; j += 512) {
        const float4 g = gt[j];
        const int pos = atomicAdd(&cursor[bin_of(g.x, xmin, invw)], 1);
        ws_gt[pos]  = g;
        ws_idx[pos] = (unsigned short)j;
    }
}

// --- main: 8 lanes per pred scan the pred's x-window from LDS ---------------
__global__ __launch_bounds__(BLOCK) void iou_max(
        const float4* __restrict__ pred,
        const float4* __restrict__ ws_gt, const unsigned short* __restrict__ ws_idx,
        const int* __restrict__ ws_bin, const float* __restrict__ ws_par,
        float* __restrict__ out) {
#pragma clang fp contract(off)
    __shared__ float4         sgt[N_GT];       // 32 KB
    __shared__ unsigned short sidx[N_GT];      //  4 KB
    __shared__ int            sbin[NBIN + 1];  //  2 KB  -> 4 blocks/CU

    for (int j = threadIdx.x; j < N_GT; j += BLOCK) {
        sgt[j]  = ws_gt[j];
        sidx[j] = ws_idx[j];
    }
    for (int j = threadIdx.x; j < NBIN + 1; j += BLOCK) sbin[j] = ws_bin[j];
    const float xmin = ws_par[0], invw = ws_par[1], mgw = ws_par[2];
    __syncthreads();

    const int  pid = blockIdx.x * PPB + (int)(threadIdx.x >> 3);
    const int  sub = threadIdx.x & (LPP - 1);
    const bool act = pid < N_PRED;
    const float4 p  = pred[act ? pid : 0];
    const float  ap = (p.z - p.x) * (p.w - p.y);

    int lo = 0, hi = 0;
    if (act) {
        // window lo has 0.5 abs slack (covers fp rounding of maxgw); any
        // over-included gt evaluates to q == 0 exactly -> harmless.
        const int bl = bin_of(p.x - mgw - 0.5f, xmin, invw);
        const int bh = bin_of(p.z, xmin, invw);
        lo = sbin[bl];
        hi = sbin[bh + 1];
    }

    float best = 0.0f;   // row max is always >= 0; (0,0) matches all-zero rows
    int   bidx = 0;
    for (int t = lo + sub; t < hi; t += LPP) {
        const float4 g  = sgt[t];
        const int    oi = sidx[t];
        const float  ag = (g.z - g.x) * (g.w - g.y);     // same fl expr as ref
        const float  w  = fmaxf(fminf(p.z, g.z) - fmaxf(p.x, g.x), 0.0f);
        const float  h  = fmaxf(fminf(p.w, g.w) - fmaxf(p.y, g.y), 0.0f);
        const float  in = w * h;
        const float  un = (ap + ag) - in;                // ref assoc order
        const float  q  = in / un;                       // exact IEEE divide
        if (q > best || (q == best && oi < bidx)) { best = q; bidx = oi; }
    }
    // lexicographic (q, -idx) reduce across the 8-lane group
#pragma unroll
    for (int s = 1; s < LPP; s <<= 1) {
        const float oq = __shfl_xor(best, s);
        const int   oi = __shfl_xor(bidx, s);
        if (oq > best || (oq == best && oi < bidx)) { best = oq; bidx = oi; }
    }
    if (act && sub == 0) {
        ((float4*)out)[pid] = p;                         // pred passthrough
        out[4 * N_PRED + 4 * N_GT + pid]          = best;
        out[4 * N_PRED + 4 * N_GT + N_PRED + pid] = (float)bidx;
    }
}

extern "C" void kernel_launch(void* const* d_in, const int* in_sizes, int n_in,
                              void* d_out, int out_size, void* d_ws, size_t ws_size,
                              hipStream_t stream) {
    const float4* pred = (const float4*)d_in[0];
    const float4* gt   = (const float4*)d_in[1];
    float* out = (float*)d_out;

    char* ws = (char*)d_ws;                       // ~41 KB used
    float4*         ws_gt  = (float4*)ws;                          // 32768 B
    unsigned short* ws_idx = (unsigned short*)(ws + 32768);        //  4096 B
    int*            ws_bin = (int*)(ws + 32768 + 4096);            //  2304 B
    float*          ws_par = (float*)(ws + 32768 + 4096 + 2304);

    build_index<<<1, 512, 0, stream>>>(gt, ws_gt, ws_idx, ws_bin, ws_par, out);

    const int gx = (N_PRED + PPB - 1) / PPB;      // 1563
    iou_max<<<gx, BLOCK, 0, stream>>>(pred, ws_gt, ws_idx, ws_bin, ws_par, out);
}

// Round 4
// 79.853 us; speedup vs baseline: 1.5981x; 1.1260x over previous
//
#include <hip/hip_runtime.h>

// OverlapCalculator: pairwise IoU [50000 x 2000] fp32, row max + argmax.
// Outputs (flat fp32): pred_bbox[200000] | gt_bbox[8000] | max[50000] | argmax-as-float[50000]
//
// 2D spatially-pruned, bit-exact vs numpy fp32:
//  q > 0 requires x-overlap (g.x < p.z and g.z > p.x) AND y-overlap
//  (g.y < p.w and g.w > p.y). Any gt failing either has w == 0 or h == 0
//  EXACTLY -> q = 0/un = 0 exactly, so skipping it cannot change the row max;
//  all-zero rows have iou[0] == 0 -> ref argmax = 0, matched by init (0,0).
//  Surviving candidates get the EXACT reference fp expression (contract off,
//  IEEE divide) + lexicographic (q, -orig_idx) reduce => bit-exact max and
//  numpy first-occurrence argmax.
//
//  build_index (1 block x 512): counting-sort gts into 32x16 (xbin,ybin)
//    cells (sorted by g.x / g.y bins), compute xmin/ymin, inv bin widths,
//    max gt width/height; write sorted gt + orig idx + cell starts to ws;
//    gt passthrough.
//  iou_max (1563 blocks x 256): stage sorted table in LDS (~39 KB -> 4
//    blocks/CU), 8 lanes per pred scan the pred's 2D window (~75 of 2000 gts
//    as ~6 contiguous runs), shfl_xor lex-reduce in the 8-lane group; pred
//    passthrough.
//
//  Window-inclusion proof sketch (bit-level): binning b(v) = clamp(floor(
//  (v-min)*inv)) is monotone in v (fp mul/floor are monotone). If g.z > p.x
//  then g.x > p.x - (g.z-g.x) >= p.x - mgw - 1e-5 (mgw = max fl(g.z-g.x),
//  values <= 1100 so fl error of the bound expr < 1e-4) > fl(p.x-mgw-0.5f)
//  -> xbin(g.x) >= bl. g.x < p.z -> xbin(g.x) <= bh. Same in y.

#define N_PRED 50000
#define N_GT   2000
#define NXB    32
#define NYB    16
#define NCELL  (NXB * NYB)     // 512
#define BLOCK  256
#define LPP    8               // lanes cooperating on one pred
#define PPB    (BLOCK / LPP)   // 32 preds per block

__device__ __forceinline__ int bin1(float v, float mn, float inv, int nb) {
    int b = (int)floorf((v - mn) * inv);
    return max(0, min(nb - 1, b));
}

// --- setup: counting-sort 2000 gts into 512 (x,y) cells; 1 block -----------
__global__ __launch_bounds__(512) void build_index(
        const float4* __restrict__ gt,
        float4* __restrict__ ws_gt, unsigned short* __restrict__ ws_idx,
        int* __restrict__ ws_cell, float* __restrict__ ws_par,
        float* __restrict__ out) {
#pragma clang fp contract(off)
    __shared__ float rxm[512], rxM[512], rym[512], ryM[512], rw[512], rh[512];
    __shared__ int   hist[NCELL], scan[NCELL], cursor[NCELL];
    __shared__ float s_par[6];
    const int tid = threadIdx.x;

    float xm = 3.4e38f, xM = -3.4e38f, ym = 3.4e38f, yM = -3.4e38f;
    float w = 0.0f, h = 0.0f;
    for (int j = tid; j < N_GT; j += 512) {
        const float4 g = gt[j];
        xm = fminf(xm, g.x); xM = fmaxf(xM, g.x);
        ym = fminf(ym, g.y); yM = fmaxf(yM, g.y);
        w  = fmaxf(w, g.z - g.x);
        h  = fmaxf(h, g.w - g.y);
        ((float4*)(out + 4 * N_PRED))[j] = g;    // gt passthrough
    }
    rxm[tid] = xm; rxM[tid] = xM; rym[tid] = ym; ryM[tid] = yM;
    rw[tid] = w;   rh[tid] = h;
    __syncthreads();
    for (int s = 256; s > 0; s >>= 1) {
        if (tid < s) {
            rxm[tid] = fminf(rxm[tid], rxm[tid + s]);
            rxM[tid] = fmaxf(rxM[tid], rxM[tid + s]);
            rym[tid] = fminf(rym[tid], rym[tid + s]);
            ryM[tid] = fmaxf(ryM[tid], ryM[tid + s]);
            rw[tid]  = fmaxf(rw[tid],  rw[tid + s]);
            rh[tid]  = fmaxf(rh[tid],  rh[tid + s]);
        }
        __syncthreads();
    }
    if (tid == 0) {
        s_par[0] = rxm[0];
        s_par[1] = (float)NXB / fmaxf(rxM[0] - rxm[0], 1e-20f);
        s_par[2] = rym[0];
        s_par[3] = (float)NYB / fmaxf(ryM[0] - rym[0], 1e-20f);
        s_par[4] = rw[0];
        s_par[5] = rh[0];
        for (int k = 0; k < 6; ++k) ws_par[k] = s_par[k];
    }
    hist[tid] = 0;                               // NCELL == blockDim
    __syncthreads();
    const float xmin = s_par[0], invx = s_par[1];
    const float ymin = s_par[2], invy = s_par[3];

    for (int j = tid; j < N_GT; j += 512) {
        const float4 g = gt[j];
        const int c = bin1(g.x, xmin, invx, NXB) * NYB +
                      bin1(g.y, ymin, invy, NYB);
        atomicAdd(&hist[c], 1);
    }
    __syncthreads();

    // inclusive Hillis-Steele scan over NCELL == 512 entries
    const int v = hist[tid];
    scan[tid] = v;
    __syncthreads();
    for (int off = 1; off < NCELL; off <<= 1) {
        const int t = (tid >= off) ? scan[tid - off] : 0;
        __syncthreads();
        scan[tid] += t;
        __syncthreads();
    }
    const int excl = scan[tid] - v;
    cursor[tid] = excl;
    ws_cell[tid] = excl;
    if (tid == NCELL - 1) ws_cell[NCELL] = scan[tid];
    __syncthreads();

    for (int j = tid; j < N_GT; j += 512) {
        const float4 g = gt[j];
        const int c = bin1(g.x, xmin, invx, NXB) * NYB +
                      bin1(g.y, ymin, invy, NYB);
        const int pos = atomicAdd(&cursor[c], 1);
        ws_gt[pos]  = g;
        ws_idx[pos] = (unsigned short)j;
    }
}

// --- main: 8 lanes per pred scan the pred's 2D window from LDS --------------
__global__ __launch_bounds__(BLOCK) void iou_max(
        const float4* __restrict__ pred,
        const float4* __restrict__ ws_gt, const unsigned short* __restrict__ ws_idx,
        const int* __restrict__ ws_cell, const float* __restrict__ ws_par,
        float* __restrict__ out) {
#pragma clang fp contract(off)
    __shared__ float4         sgt[N_GT];        // 32 KB
    __shared__ unsigned short sidx[N_GT];       //  4 KB
    __shared__ int            scell[NCELL + 1]; //  2 KB -> 4 blocks/CU

    for (int j = threadIdx.x; j < N_GT; j += BLOCK) {
        sgt[j]  = ws_gt[j];
        sidx[j] = ws_idx[j];
    }
    for (int j = threadIdx.x; j < NCELL + 1; j += BLOCK) scell[j] = ws_cell[j];
    const float xmin = ws_par[0], invx = ws_par[1];
    const float ymin = ws_par[2], invy = ws_par[3];
    const float mgw  = ws_par[4], mgh  = ws_par[5];
    __syncthreads();

    const int  pid = blockIdx.x * PPB + (int)(threadIdx.x >> 3);
    const int  sub = threadIdx.x & (LPP - 1);
    const bool act = pid < N_PRED;
    const float4 p  = pred[act ? pid : 0];
    const float  ap = (p.z - p.x) * (p.w - p.y);

    int bl = 0, bh = -1, yl = 0, yh1 = 0;
    if (act) {
        // 0.5 abs slack covers fp rounding of mgw/mgh and of the bound expr;
        // any over-included gt evaluates to q == 0 exactly -> harmless.
        bl  = bin1(p.x - mgw - 0.5f, xmin, invx, NXB);
        bh  = bin1(p.z,              xmin, invx, NXB);
        yl  = bin1(p.y - mgh - 0.5f, ymin, invy, NYB);
        yh1 = bin1(p.w,              ymin, invy, NYB) + 1;
    }

    float best = 0.0f;   // row max >= 0; (0,0) matches all-zero rows
    int   bidx = 0;
    for (int b = bl; b <= bh; ++b) {
        const int rlo = scell[b * NYB + yl];
        const int rhi = scell[b * NYB + yh1];
        for (int t = rlo + sub; t < rhi; t += LPP) {
            const float4 g  = sgt[t];
            const int    oi = sidx[t];
            const float  ag = (g.z - g.x) * (g.w - g.y);   // same fl expr as ref
            const float  w  = fmaxf(fminf(p.z, g.z) - fmaxf(p.x, g.x), 0.0f);
            const float  h  = fmaxf(fminf(p.w, g.w) - fmaxf(p.y, g.y), 0.0f);
            const float  in = w * h;
            const float  un = (ap + ag) - in;              // ref assoc order
            const float  q  = in / un;                     // exact IEEE divide
            if (q > best || (q == best && oi < bidx)) { best = q; bidx = oi; }
        }
    }
    // lexicographic (q, -idx) reduce across the 8-lane group
#pragma unroll
    for (int s = 1; s < LPP; s <<= 1) {
        const float oq = __shfl_xor(best, s);
        const int   oi = __shfl_xor(bidx, s);
        if (oq > best || (oq == best && oi < bidx)) { best = oq; bidx = oi; }
    }
    if (act && sub == 0) {
        ((float4*)out)[pid] = p;                           // pred passthrough
        out[4 * N_PRED + 4 * N_GT + pid]          = best;
        out[4 * N_PRED + 4 * N_GT + N_PRED + pid] = (float)bidx;
    }
}

extern "C" void kernel_launch(void* const* d_in, const int* in_sizes, int n_in,
                              void* d_out, int out_size, void* d_ws, size_t ws_size,
                              hipStream_t stream) {
    const float4* pred = (const float4*)d_in[0];
    const float4* gt   = (const float4*)d_in[1];
    float* out = (float*)d_out;

    char* ws = (char*)d_ws;                       // ~39 KB used
    float4*         ws_gt   = (float4*)ws;                         // 32768 B
    unsigned short* ws_idx  = (unsigned short*)(ws + 32768);       //  4096 B
    int*            ws_cell = (int*)(ws + 32768 + 4096);           //  2304 B
    float*          ws_par  = (float*)(ws + 32768 + 4096 + 2304);

    build_index<<<1, 512, 0, stream>>>(gt, ws_gt, ws_idx, ws_cell, ws_par, out);

    const int gx = (N_PRED + PPB - 1) / PPB;      // 1563
    iou_max<<<gx, BLOCK, 0, stream>>>(pred, ws_gt, ws_idx, ws_cell, ws_par, out);
}

// Round 5
// 78.248 us; speedup vs baseline: 1.6308x; 1.0205x over previous
//
#include <hip/hip_runtime.h>

// OverlapCalculator: pairwise IoU [50000 x 2000] fp32, row max + argmax.
// Outputs (flat fp32): pred_bbox[200000] | gt_bbox[8000] | max[50000] | argmax-as-float[50000]
//
// 2D spatially-pruned, bit-exact vs numpy fp32:
//  q > 0 requires x-overlap (g.x < p.z and g.z > p.x) AND y-overlap
//  (g.y < p.w and g.w > p.y). Any gt failing either has w == 0 or h == 0
//  EXACTLY -> q = 0/un = 0 exactly, so skipping it cannot change the row max;
//  all-zero rows have iou[0] == 0 -> ref argmax = 0, matched by init (0,0).
//  Surviving candidates get the EXACT reference fp expression (contract off,
//  IEEE divide) + lexicographic (q, -orig_idx) reduce => bit-exact max and
//  numpy first-occurrence argmax.  The in > 0 divide guard only skips
//  candidates whose q == 0 exactly (in == 0) -> harmless.
//
//  build_index (1 block x 512, wave-shfl reductions/scans, ~5 barriers):
//    counting-sort gts into 32x16 (xbin,ybin) cells, compute xmin/ymin,
//    inv bin widths, max gt width/height; write sorted gt + orig idx +
//    cell starts to ws; gt passthrough. Each thread caches its <=4 gts in
//    registers across all phases.
//  iou_max (391 blocks x 512): stage sorted table in LDS (~39 KB), 8 lanes
//    per pred, 2 preds sequentially per lane-group -> 128 preds/block
//    (LDS reuse 4.8x, single scheduling round). Window scan over ~6
//    contiguous runs (~75 of 2000 gts), shfl_xor lex-reduce; pred
//    passthrough.
//
//  Window-inclusion proof sketch (bit-level): binning b(v) = clamp(floor(
//  (v-min)*inv)) is monotone in v (fp mul/floor are monotone). If g.z > p.x
//  then g.x > p.x - (g.z-g.x) >= p.x - mgw - 1e-5 (mgw = max fl(g.z-g.x),
//  values <= 1100 so fl error of the bound expr < 1e-4) > fl(p.x-mgw-0.5f)
//  -> xbin(g.x) >= bl. g.x < p.z -> xbin(g.x) <= bh. Same in y.

#define N_PRED 50000
#define N_GT   2000
#define NXB    32
#define NYB    16
#define NCELL  (NXB * NYB)     // 512
#define BLOCK  512
#define LPP    8               // lanes cooperating on one pred
#define NGRP   (BLOCK / LPP)   // 64 lane-groups per block
#define PPT    2               // preds per lane-group (sequential)
#define PPB    (NGRP * PPT)    // 128 preds per block

__device__ __forceinline__ int bin1(float v, float mn, float inv, int nb) {
    int b = (int)floorf((v - mn) * inv);
    return max(0, min(nb - 1, b));
}

// --- setup: counting-sort 2000 gts into 512 (x,y) cells; 1 block x 512 ------
__global__ __launch_bounds__(512) void build_index(
        const float4* __restrict__ gt,
        float4* __restrict__ ws_gt, unsigned short* __restrict__ ws_idx,
        int* __restrict__ ws_cell, float* __restrict__ ws_par,
        float* __restrict__ out) {
#pragma clang fp contract(off)
    __shared__ float wred[8][6];
    __shared__ int   wsum[8];
    __shared__ float s_par[6];
    __shared__ int   hist[NCELL];    // doubles as cursor after scan
    const int tid  = threadIdx.x;
    const int lane = tid & 63;
    const int wv   = tid >> 6;       // 8 waves

    hist[tid] = 0;                   // NCELL == blockDim == 512

    // load + cache this thread's gts (<=4), partial min/max, gt passthrough
    float4 gr[4];
    int    nloc = 0;
    float xm = 3.4e38f, xM = -3.4e38f, ym = 3.4e38f, yM = -3.4e38f;
    float w = 0.0f, h = 0.0f;
    for (int j = tid; j < N_GT; j += 512) {
        const float4 g = gt[j];
        gr[nloc++] = g;
        xm = fminf(xm, g.x); xM = fmaxf(xM, g.x);
        ym = fminf(ym, g.y); yM = fmaxf(yM, g.y);
        w  = fmaxf(w, g.z - g.x);
        h  = fmaxf(h, g.w - g.y);
        ((float4*)(out + 4 * N_PRED))[j] = g;    // gt passthrough
    }
    // wave-level butterfly reductions (no barriers)
#pragma unroll
    for (int s = 1; s < 64; s <<= 1) {
        xm = fminf(xm, __shfl_xor(xm, s));
        xM = fmaxf(xM, __shfl_xor(xM, s));
        ym = fminf(ym, __shfl_xor(ym, s));
        yM = fmaxf(yM, __shfl_xor(yM, s));
        w  = fmaxf(w,  __shfl_xor(w,  s));
        h  = fmaxf(h,  __shfl_xor(h,  s));
    }
    if (lane == 0) {
        wred[wv][0] = xm; wred[wv][1] = xM; wred[wv][2] = ym;
        wred[wv][3] = yM; wred[wv][4] = w;  wred[wv][5] = h;
    }
    __syncthreads();                                            // B1
    if (tid == 0) {
        float a0 = wred[0][0], a1 = wred[0][1], a2 = wred[0][2];
        float a3 = wred[0][3], a4 = wred[0][4], a5 = wred[0][5];
        for (int k = 1; k < 8; ++k) {
            a0 = fminf(a0, wred[k][0]); a1 = fmaxf(a1, wred[k][1]);
            a2 = fminf(a2, wred[k][2]); a3 = fmaxf(a3, wred[k][3]);
            a4 = fmaxf(a4, wred[k][4]); a5 = fmaxf(a5, wred[k][5]);
        }
        s_par[0] = a0;
        s_par[1] = (float)NXB / fmaxf(a1 - a0, 1e-20f);
        s_par[2] = a2;
        s_par[3] = (float)NYB / fmaxf(a3 - a2, 1e-20f);
        s_par[4] = a4;
        s_par[5] = a5;
        for (int k = 0; k < 6; ++k) ws_par[k] = s_par[k];
    }
    __syncthreads();                                            // B2
    const float xmin = s_par[0], invx = s_par[1];
    const float ymin = s_par[2], invy = s_par[3];

    int cellr[4];
    for (int i = 0; i < nloc; ++i) {
        cellr[i] = bin1(gr[i].x, xmin, invx, NXB) * NYB +
                   bin1(gr[i].y, ymin, invy, NYB);
        atomicAdd(&hist[cellr[i]], 1);
    }
    __syncthreads();                                            // B3

    // two-level inclusive scan over NCELL == 512 (wave shfl + 8 wave sums)
    const int v = hist[tid];
    int x = v;
#pragma unroll
    for (int s = 1; s < 64; s <<= 1) {
        const int t = __shfl_up(x, s);
        if (lane >= s) x += t;
    }
    if (lane == 63) wsum[wv] = x;
    __syncthreads();                                            // B4
    if (wv == 0) {
        int t = (lane < 8) ? wsum[lane] : 0;
#pragma unroll
        for (int s = 1; s < 8; s <<= 1) {
            const int u = __shfl_up(t, s);
            if (lane >= s) t += u;
        }
        if (lane < 8) wsum[lane] = t;
    }
    __syncthreads();                                            // B5
    const int incl = x + (wv ? wsum[wv - 1] : 0);
    const int excl = incl - v;
    ws_cell[tid] = excl;
    if (tid == NCELL - 1) ws_cell[NCELL] = incl;                // == N_GT
    hist[tid] = excl;                                           // -> cursor
    __syncthreads();                                            // B6

    for (int i = 0; i < nloc; ++i) {
        const int pos = atomicAdd(&hist[cellr[i]], 1);
        ws_gt[pos]  = gr[i];
        ws_idx[pos] = (unsigned short)(tid + i * 512);
    }
}

// --- main: 8 lanes per pred, 2 preds per group, table in LDS ----------------
__global__ __launch_bounds__(BLOCK) void iou_max(
        const float4* __restrict__ pred,
        const float4* __restrict__ ws_gt, const unsigned short* __restrict__ ws_idx,
        const int* __restrict__ ws_cell, const float* __restrict__ ws_par,
        float* __restrict__ out) {
#pragma clang fp contract(off)
    __shared__ float4         sgt[N_GT];        // 32 KB
    __shared__ unsigned short sidx[N_GT];       //  4 KB
    __shared__ int            scell[NCELL + 1]; //  2 KB

    for (int j = threadIdx.x; j < N_GT; j += BLOCK) {
        sgt[j]  = ws_gt[j];
        sidx[j] = ws_idx[j];
    }
    for (int j = threadIdx.x; j < NCELL + 1; j += BLOCK) scell[j] = ws_cell[j];
    const float xmin = ws_par[0], invx = ws_par[1];
    const float ymin = ws_par[2], invy = ws_par[3];
    const float mgw  = ws_par[4], mgh  = ws_par[5];
    __syncthreads();

    const int grp = (int)(threadIdx.x >> 3);        // 0..63
    const int sub = threadIdx.x & (LPP - 1);

#pragma unroll
    for (int k = 0; k < PPT; ++k) {
        const int  pid = blockIdx.x * PPB + k * NGRP + grp;
        const bool act = pid < N_PRED;
        const float4 p  = pred[act ? pid : 0];
        const float  ap = (p.z - p.x) * (p.w - p.y);

        int bl = 0, bh = -1, yl = 0, yh1 = 0;
        if (act) {
            // 0.5 abs slack covers fp rounding of mgw/mgh and the bound expr;
            // any over-included gt evaluates to q == 0 exactly -> harmless.
            bl  = bin1(p.x - mgw - 0.5f, xmin, invx, NXB);
            bh  = bin1(p.z,              xmin, invx, NXB);
            yl  = bin1(p.y - mgh - 0.5f, ymin, invy, NYB);
            yh1 = bin1(p.w,              ymin, invy, NYB) + 1;
        }

        float best = 0.0f;   // row max >= 0; (0,0) matches all-zero rows
        int   bidx = 0;
        for (int b = bl; b <= bh; ++b) {
            const int rlo = scell[b * NYB + yl];
            const int rhi = scell[b * NYB + yh1];
            for (int t = rlo + sub; t < rhi; t += LPP) {
                const float4 g  = sgt[t];
                const int    oi = sidx[t];
                const float  ag = (g.z - g.x) * (g.w - g.y); // same fl expr as ref
                const float  w  = fmaxf(fminf(p.z, g.z) - fmaxf(p.x, g.x), 0.0f);
                const float  h  = fmaxf(fminf(p.w, g.w) - fmaxf(p.y, g.y), 0.0f);
                const float  in = w * h;
                if (in > 0.0f) {                 // in==0 -> q==0 exactly: skip
                    const float un = (ap + ag) - in;         // ref assoc order
                    const float q  = in / un;                // exact IEEE divide
                    if (q > best || (q == best && oi < bidx)) { best = q; bidx = oi; }
                }
            }
        }
        // lexicographic (q, -idx) reduce across the 8-lane group
#pragma unroll
        for (int s = 1; s < LPP; s <<= 1) {
            const float oq = __shfl_xor(best, s);
            const int   oi = __shfl_xor(bidx, s);
            if (oq > best || (oq == best && oi < bidx)) { best = oq; bidx = oi; }
        }
        if (act && sub == 0) {
            ((float4*)out)[pid] = p;                         // pred passthrough
            out[4 * N_PRED + 4 * N_GT + pid]          = best;
            out[4 * N_PRED + 4 * N_GT + N_PRED + pid] = (float)bidx;
        }
    }
}

extern "C" void kernel_launch(void* const* d_in, const int* in_sizes, int n_in,
                              void* d_out, int out_size, void* d_ws, size_t ws_size,
                              hipStream_t stream) {
    const float4* pred = (const float4*)d_in[0];
    const float4* gt   = (const float4*)d_in[1];
    float* out = (float*)d_out;

    char* ws = (char*)d_ws;                       // ~39 KB used
    float4*         ws_gt   = (float4*)ws;                         // 32768 B
    unsigned short* ws_idx  = (unsigned short*)(ws + 32768);       //  4096 B
    int*            ws_cell = (int*)(ws + 32768 + 4096);           //  2304 B
    float*          ws_par  = (float*)(ws + 32768 + 4096 + 2304);

    build_index<<<1, 512, 0, stream>>>(gt, ws_gt, ws_idx, ws_cell, ws_par, out);

    const int gx = (N_PRED + PPB - 1) / PPB;      // 391
    iou_max<<<gx, BLOCK, 0, stream>>>(pred, ws_gt, ws_idx, ws_cell, ws_par, out);
}